// Round 5
// baseline (777.064 us; speedup 1.0000x reference)
//
#include <hip/hip_runtime.h>
#include <hip/hip_bf16.h>
#include <cstddef>

// GCN: h0 = relu(spmm(x@W0^T)); h1 = relu(spmm(h0@W1^T)); out = spmm(h1@W2^T)
// R5: XCD-sliced CSR build. Scatter writes go to 8 slice-major regions keyed by
// blockIdx%8 (XCD round-robin heuristic) so each 64B line is filled by one XCD
// while L2-resident (kills the 8x write amplification seen in R4's scatter_k).
// A reorder pass then produces row-contiguous CSR; GEMM/SpMM unchanged from R4.

typedef unsigned short ushort_t;
using frag_t = __attribute__((ext_vector_type(8))) short;   // 8 bf16
using accf4 = __attribute__((ext_vector_type(4))) float;    // 4 fp32

__device__ __forceinline__ ushort_t f2bf(float f) {
    unsigned int u = __float_as_uint(f);
    u += 0x7FFF + ((u >> 16) & 1);   // RNE
    return (ushort_t)(u >> 16);
}
__device__ __forceinline__ float bf2f(ushort_t u) {
    return __uint_as_float((unsigned int)u << 16);
}

// ---------------- generic small kernels ----------------

__global__ __launch_bounds__(256) void zero_i32(int* p, int n) {
    int i = blockIdx.x * 256 + threadIdx.x;
    if (i < n) p[i] = 0;
}

__global__ __launch_bounds__(256) void block_totals(const int* __restrict__ counts,
                                                    int* __restrict__ bsums, int n) {
    __shared__ int s[256];
    int t = threadIdx.x;
    int i = blockIdx.x * 256 + t;
    s[t] = (i < n) ? counts[i] : 0;
    __syncthreads();
    for (int off = 128; off > 0; off >>= 1) {
        if (t < off) s[t] += s[t + off];
        __syncthreads();
    }
    if (t == 0) bsums[blockIdx.x] = s[0];
}

// single block, 512 threads: exclusive scan of nb (<=512) values in place
__global__ __launch_bounds__(512) void scan_sums(int* bsums, int nb) {
    __shared__ int s[512];
    int t = threadIdx.x;
    int v = (t < nb) ? bsums[t] : 0;
    s[t] = v;
    __syncthreads();
    for (int off = 1; off < 512; off *= 2) {
        int u = (t >= off) ? s[t - off] : 0;
        __syncthreads();
        s[t] += u;
        __syncthreads();
    }
    if (t < nb) bsums[t] = s[t] - v;  // exclusive
}

// exclusive scan with per-block offsets; optionally mirrors to out1 and writes
// a tail value (array total) at *tail.
__global__ __launch_bounds__(256) void scan_wo(const int* __restrict__ data,
                                               const int* __restrict__ offs,
                                               int* __restrict__ out0,
                                               int* __restrict__ out1,
                                               int* __restrict__ tail, int tailval,
                                               int m) {
    __shared__ int s[256];
    int t = threadIdx.x;
    int i = blockIdx.x * 256 + t;
    int v = (i < m) ? data[i] : 0;
    s[t] = v;
    __syncthreads();
    for (int off = 1; off < 256; off *= 2) {
        int u = (t >= off) ? s[t - off] : 0;
        __syncthreads();
        s[t] += u;
        __syncthreads();
    }
    int excl = s[t] - v + offs[blockIdx.x];
    if (i < m) {
        out0[i] = excl;
        if (out1) out1[i] = excl;
    }
    if (i == 0 && tail) *tail = tailval;
}

// ---------------- XCD-sliced CSR build ----------------

__global__ __launch_bounds__(256) void hist8_k(const int* __restrict__ rows,
                                               int* __restrict__ cnt8, int n, int ne) {
    int e = blockIdx.x * 256 + threadIdx.x;
    if (e >= ne) return;
    int s = blockIdx.x & 7;
    atomicAdd(&cnt8[s * n + rows[e]], 1);
}

__global__ __launch_bounds__(256) void scatter8_k(const int* __restrict__ rows,
                                                  const int* __restrict__ cols,
                                                  const float* __restrict__ vals,
                                                  int* __restrict__ cur8,
                                                  int2* __restrict__ es1, int n, int ne) {
    int e = blockIdx.x * 256 + threadIdx.x;
    if (e >= ne) return;
    int s = blockIdx.x & 7;
    int r = rows[e];
    int p = atomicAdd(&cur8[s * n + r], 1);
    es1[p] = make_int2(cols[e], __float_as_int(vals[e]));
}

// row counts from slice segment lengths (no atomics)
__global__ __launch_bounds__(256) void rowcnt_k(const int* __restrict__ rp8,
                                                int* __restrict__ cnt_row, int n) {
    int i = blockIdx.x * 256 + threadIdx.x;
    if (i >= n) return;
    int c = 0;
#pragma unroll
    for (int s = 0; s < 8; s++) c += rp8[s * n + i + 1] - rp8[s * n + i];
    cnt_row[i] = c;
}

// concatenate each row's 8 slice segments into row-contiguous CSR.
// 8 lanes per row, 32 rows per block; whole 8-lane group shares one row.
__global__ __launch_bounds__(256) void reorder_k(const int* __restrict__ rp8,
                                                 const int* __restrict__ row_ptr,
                                                 const int2* __restrict__ es1,
                                                 int2* __restrict__ es2, int n) {
    int tid = threadIdx.x;
    int row = blockIdx.x * 32 + (tid >> 3);
    int s = tid & 7;
    if (row >= n) return;
    int st = rp8[s * n + row];
    int en = rp8[s * n + row + 1];
    int len = en - st;
    int incl = len;
#pragma unroll
    for (int d = 1; d < 8; d <<= 1) {
        int u = __shfl_up(incl, d, 8);
        if ((tid & 7) >= d) incl += u;
    }
    int dst = row_ptr[row] + incl - len;
    for (int p = st; p < en; p++) es2[dst++] = es1[p];
}

// ---------------- weight convert ----------------

__global__ __launch_bounds__(256) void f32_to_bf16_k(const float* __restrict__ a,
                                                     ushort_t* __restrict__ b, int n) {
    int i = blockIdx.x * 256 + threadIdx.x;
    if (i < n) b[i] = f2bf(a[i]);
}

// ---------------- bf16 MFMA GEMM: C[M,N] = A[M,K] * W[N,K]^T ----------------
// 2-barrier pipelined K-loop: prefetch tile t+1 into registers while MFMAing
// tile t from LDS. ABF16: A already bf16; else fp32 converted at LDS write.

template <int K, int N, int BM, int BN, int BK, bool ABF16>
__global__ __launch_bounds__(256) void gemm_bf16(const void* __restrict__ Av,
                                                 const ushort_t* __restrict__ Wb,
                                                 ushort_t* __restrict__ C, int M) {
    constexpr int WM = BM / 2, WN = BN / 2;
    constexpr int TI = WM / 16, TJ = WN / 16;
    constexpr int LDA = BK + 8;
    constexpr int T = K / BK;
    constexpr int A_PER_F = BM * BK / 4 / 256;
    constexpr int A_PER_B = BM * BK / 8 / 256;
    constexpr int B_PER = BN * BK / 8 / 256;

    __shared__ __align__(16) ushort_t As[BM][LDA];
    __shared__ __align__(16) ushort_t Bs[BN][LDA];

    const int tid = threadIdx.x;
    const int lane = tid & 63;
    const int wid = tid >> 6;
    const int wm = wid >> 1, wn = wid & 1;
    const int rowBase = blockIdx.x * BM;
    const int lrow = lane & 15, kq = lane >> 4;

    float4 aF[ABF16 ? 1 : A_PER_F];
    uint4 aB[ABF16 ? A_PER_B : 1];
    uint4 bR[B_PER];

    auto loadTile = [&](int k0) {
        if constexpr (ABF16) {
            const ushort_t* A = (const ushort_t*)Av;
#pragma unroll
            for (int i = 0; i < A_PER_B; i++) {
                int idx = tid + i * 256;
                int r = idx / (BK / 8), c8 = idx % (BK / 8);
                int grow = rowBase + r;
                aB[i] = (grow < M) ? *(const uint4*)(A + (size_t)grow * K + k0 + c8 * 8)
                                   : make_uint4(0, 0, 0, 0);
            }
        } else {
            const float* A = (const float*)Av;
#pragma unroll
            for (int i = 0; i < A_PER_F; i++) {
                int idx = tid + i * 256;
                int r = idx / (BK / 4), c4 = idx % (BK / 4);
                int grow = rowBase + r;
                aF[i] = (grow < M) ? *(const float4*)(A + (size_t)grow * K + k0 + c4 * 4)
                                   : make_float4(0.f, 0.f, 0.f, 0.f);
            }
        }
#pragma unroll
        for (int i = 0; i < B_PER; i++) {
            int idx = tid + i * 256;
            int r = idx / (BK / 8), c8 = idx % (BK / 8);
            bR[i] = *(const uint4*)(Wb + (size_t)r * K + k0 + c8 * 8);
        }
    };
    auto storeTile = [&]() {
        if constexpr (ABF16) {
#pragma unroll
            for (int i = 0; i < A_PER_B; i++) {
                int idx = tid + i * 256;
                int r = idx / (BK / 8), c8 = idx % (BK / 8);
                *(uint4*)&As[r][c8 * 8] = aB[i];
            }
        } else {
#pragma unroll
            for (int i = 0; i < A_PER_F; i++) {
                int idx = tid + i * 256;
                int r = idx / (BK / 4), c4 = idx % (BK / 4);
                ushort_t p[4] = {f2bf(aF[i].x), f2bf(aF[i].y), f2bf(aF[i].z), f2bf(aF[i].w)};
                *(uint2*)&As[r][c4 * 4] = *(uint2*)p;
            }
        }
#pragma unroll
        for (int i = 0; i < B_PER; i++) {
            int idx = tid + i * 256;
            int r = idx / (BK / 8), c8 = idx % (BK / 8);
            *(uint4*)&Bs[r][c8 * 8] = bR[i];
        }
    };

    accf4 acc[TI][TJ];
#pragma unroll
    for (int i = 0; i < TI; i++)
#pragma unroll
        for (int j = 0; j < TJ; j++) acc[i][j] = accf4{0.f, 0.f, 0.f, 0.f};

    loadTile(0);
    storeTile();
    __syncthreads();

    for (int t = 0; t < T; t++) {
        if (t + 1 < T) loadTile((t + 1) * BK);   // in flight during MFMA
#pragma unroll
        for (int ks = 0; ks < BK / 32; ks++) {
            const int kb = ks * 32 + kq * 8;
            frag_t a[TI], b[TJ];
#pragma unroll
            for (int i = 0; i < TI; i++)
                a[i] = *(const frag_t*)&As[wm * WM + i * 16 + lrow][kb];
#pragma unroll
            for (int j = 0; j < TJ; j++)
                b[j] = *(const frag_t*)&Bs[wn * WN + j * 16 + lrow][kb];
#pragma unroll
            for (int i = 0; i < TI; i++)
#pragma unroll
                for (int j = 0; j < TJ; j++)
                    acc[i][j] = __builtin_amdgcn_mfma_f32_16x16x32_bf16(
                        a[i], b[j], acc[i][j], 0, 0, 0);
        }
        __syncthreads();
        if (t + 1 < T) {
            storeTile();
            __syncthreads();
        }
    }

    // epilogue: C/D layout col=lane&15, row=(lane>>4)*4+reg; write bf16
#pragma unroll
    for (int i = 0; i < TI; i++) {
#pragma unroll
        for (int j = 0; j < TJ; j++) {
            int col = wn * WN + j * 16 + lrow;
#pragma unroll
            for (int r = 0; r < 4; r++) {
                int grow = rowBase + wm * WM + i * 16 + kq * 4 + r;
                if (grow < M) C[(size_t)grow * N + col] = f2bf(acc[i][j][r]);
            }
        }
    }
}

// ---------------- SpMM (CSR, wave per row, bf16 gather, x4 unroll) ----------

template <bool RELU>
__global__ __launch_bounds__(256) void spmm_csr_128(const int* __restrict__ row_ptr,
                                                    const int2* __restrict__ es,
                                                    const ushort_t* __restrict__ G,
                                                    ushort_t* __restrict__ H, int n) {
    int row = blockIdx.x * 4 + (threadIdx.x >> 6);
    int lane = threadIdx.x & 63;
    if (row >= n) return;
    int s = row_ptr[row];
    int e = row_ptr[row + 1];
    float a0 = 0.f, a1 = 0.f;
    int p = s;
    for (; p + 3 < e; p += 4) {
        int2 e0 = es[p], e1 = es[p + 1], e2 = es[p + 2], e3 = es[p + 3];
        unsigned u0 = *(const unsigned*)(G + (size_t)e0.x * 128 + lane * 2);
        unsigned u1 = *(const unsigned*)(G + (size_t)e1.x * 128 + lane * 2);
        unsigned u2 = *(const unsigned*)(G + (size_t)e2.x * 128 + lane * 2);
        unsigned u3 = *(const unsigned*)(G + (size_t)e3.x * 128 + lane * 2);
        float v0 = __int_as_float(e0.y), v1 = __int_as_float(e1.y);
        float v2 = __int_as_float(e2.y), v3 = __int_as_float(e3.y);
        a0 += v0 * bf2f((ushort_t)(u0 & 0xffff)); a1 += v0 * bf2f((ushort_t)(u0 >> 16));
        a0 += v1 * bf2f((ushort_t)(u1 & 0xffff)); a1 += v1 * bf2f((ushort_t)(u1 >> 16));
        a0 += v2 * bf2f((ushort_t)(u2 & 0xffff)); a1 += v2 * bf2f((ushort_t)(u2 >> 16));
        a0 += v3 * bf2f((ushort_t)(u3 & 0xffff)); a1 += v3 * bf2f((ushort_t)(u3 >> 16));
    }
    for (; p < e; p++) {
        int2 e0 = es[p];
        unsigned u0 = *(const unsigned*)(G + (size_t)e0.x * 128 + lane * 2);
        float v0 = __int_as_float(e0.y);
        a0 += v0 * bf2f((ushort_t)(u0 & 0xffff)); a1 += v0 * bf2f((ushort_t)(u0 >> 16));
    }
    if (RELU) { a0 = fmaxf(a0, 0.f); a1 = fmaxf(a1, 0.f); }
    unsigned packed = (unsigned)f2bf(a0) | ((unsigned)f2bf(a1) << 16);
    *(unsigned*)(H + (size_t)row * 128 + lane * 2) = packed;
}

__global__ __launch_bounds__(256) void spmm_csr_64f(const int* __restrict__ row_ptr,
                                                    const int2* __restrict__ es,
                                                    const ushort_t* __restrict__ G,
                                                    float* __restrict__ H, int n) {
    int row = blockIdx.x * 4 + (threadIdx.x >> 6);
    int lane = threadIdx.x & 63;
    if (row >= n) return;
    int s = row_ptr[row];
    int e = row_ptr[row + 1];
    float a0 = 0.f;
    int p = s;
    for (; p + 3 < e; p += 4) {
        int2 e0 = es[p], e1 = es[p + 1], e2 = es[p + 2], e3 = es[p + 3];
        float g0 = bf2f(G[(size_t)e0.x * 64 + lane]);
        float g1 = bf2f(G[(size_t)e1.x * 64 + lane]);
        float g2 = bf2f(G[(size_t)e2.x * 64 + lane]);
        float g3 = bf2f(G[(size_t)e3.x * 64 + lane]);
        a0 += __int_as_float(e0.y) * g0 + __int_as_float(e1.y) * g1 +
              __int_as_float(e2.y) * g2 + __int_as_float(e3.y) * g3;
    }
    for (; p < e; p++) {
        a0 += __int_as_float(es[p].y) * bf2f(G[(size_t)es[p].x * 64 + lane]);
    }
    H[(size_t)row * 64 + lane] = a0;
}

static inline size_t align_up(size_t x, size_t a) { return (x + a - 1) & ~(a - 1); }

extern "C" void kernel_launch(void* const* d_in, const int* in_sizes, int n_in,
                              void* d_out, int out_size, void* d_ws, size_t ws_size,
                              hipStream_t stream) {
    const float* x = (const float*)d_in[0];
    const int* rows = (const int*)d_in[1];
    const int* cols = (const int*)d_in[2];
    const float* vals = (const float*)d_in[3];
    const float* W0 = (const float*)d_in[4];
    const float* W1 = (const float*)d_in[5];
    const float* W2 = (const float*)d_in[6];
    float* out = (float*)d_out;

    const int IN = 512, HID = 128, OUT = 64;
    const int n = in_sizes[0] / IN;   // 100000
    const int ne = in_sizes[1];       // 1600000

    // workspace carve-up
    char* ws = (char*)d_ws;
    size_t off = 0;
    ushort_t* g = (ushort_t*)(ws + off); off = align_up(off + (size_t)n * HID * 2, 512);
    ushort_t* h = (ushort_t*)(ws + off); off = align_up(off + (size_t)n * HID * 2, 512);
    int2* es1 = (int2*)(ws + off); off = align_up(off + (size_t)ne * 8, 512);
    int2* es2 = (int2*)(ws + off); off = align_up(off + (size_t)ne * 8, 512);
    int* cnt8 = (int*)(ws + off); off = align_up(off + (size_t)8 * n * 4, 512);
    int* rp8 = (int*)(ws + off); off = align_up(off + ((size_t)8 * n + 1) * 4, 512);
    int* cur8 = (int*)(ws + off); off = align_up(off + (size_t)8 * n * 4, 512);
    int* cnt_row = (int*)(ws + off); off = align_up(off + (size_t)n * 4, 512);
    int* row_ptr = (int*)(ws + off); off = align_up(off + (size_t)(n + 1) * 4, 512);
    int* bsum0 = (int*)(ws + off); off = align_up(off + 4096 * 4, 512);
    int* bsum1 = (int*)(ws + off); off = align_up(off + 512 * 4, 512);
    int* off0 = (int*)(ws + off); off = align_up(off + 4096 * 4, 512);
    int* bsums_r = (int*)(ws + off); off = align_up(off + 512 * 4, 512);
    ushort_t* Wb0 = (ushort_t*)(ws + off); off = align_up(off + (size_t)HID * IN * 2, 512);
    ushort_t* Wb1 = (ushort_t*)(ws + off); off = align_up(off + (size_t)HID * HID * 2, 512);
    ushort_t* Wb2 = (ushort_t*)(ws + off); off = align_up(off + (size_t)OUT * HID * 2, 512);

    const int nb = (n + 255) / 256;        // 391
    const int eb = (ne + 255) / 256;       // 6250
    const int m8 = 8 * n;                  // 800000
    const int nb8 = (m8 + 255) / 256;      // 3125
    const int nb8b = (nb8 + 255) / 256;    // 13

    // ---- sliced CSR build ----
    zero_i32<<<nb8, 256, 0, stream>>>(cnt8, m8);
    hist8_k<<<eb, 256, 0, stream>>>(rows, cnt8, n, ne);
    block_totals<<<nb8, 256, 0, stream>>>(cnt8, bsum0, m8);
    block_totals<<<nb8b, 256, 0, stream>>>(bsum0, bsum1, nb8);
    scan_sums<<<1, 512, 0, stream>>>(bsum1, nb8b);
    scan_wo<<<nb8b, 256, 0, stream>>>(bsum0, bsum1, off0, nullptr, nullptr, 0, nb8);
    scan_wo<<<nb8, 256, 0, stream>>>(cnt8, off0, rp8, cur8, rp8 + m8, ne, m8);
    scatter8_k<<<eb, 256, 0, stream>>>(rows, cols, vals, cur8, es1, n, ne);

    // ---- row_ptr from slice segment lengths ----
    rowcnt_k<<<nb, 256, 0, stream>>>(rp8, cnt_row, n);
    block_totals<<<nb, 256, 0, stream>>>(cnt_row, bsums_r, n);
    scan_sums<<<1, 512, 0, stream>>>(bsums_r, nb);
    scan_wo<<<nb, 256, 0, stream>>>(cnt_row, bsums_r, row_ptr, nullptr, row_ptr + n, ne, n);

    // ---- reorder to row-contiguous CSR ----
    reorder_k<<<(n + 31) / 32, 256, 0, stream>>>(rp8, row_ptr, es1, es2, n);

    // ---- weights -> bf16 ----
    f32_to_bf16_k<<<(HID * IN + 255) / 256, 256, 0, stream>>>(W0, Wb0, HID * IN);
    f32_to_bf16_k<<<(HID * HID + 255) / 256, 256, 0, stream>>>(W1, Wb1, HID * HID);
    f32_to_bf16_k<<<(OUT * HID + 255) / 256, 256, 0, stream>>>(W2, Wb2, OUT * HID);

    const int gblocks = (n + 127) / 128;
    const int sblocks = (n + 3) / 4;

    // ---- layer 0 ----
    gemm_bf16<512, 128, 128, 128, 64, false><<<gblocks, 256, 0, stream>>>(x, Wb0, g, n);
    spmm_csr_128<true><<<sblocks, 256, 0, stream>>>(row_ptr, es2, g, h, n);

    // ---- layer 1 ----
    gemm_bf16<128, 128, 128, 128, 64, true><<<gblocks, 256, 0, stream>>>(h, Wb1, g, n);
    spmm_csr_128<true><<<sblocks, 256, 0, stream>>>(row_ptr, es2, g, h, n);

    // ---- layer 2 ----
    gemm_bf16<128, 64, 128, 64, 64, true><<<gblocks, 256, 0, stream>>>(h, Wb2, g, n);
    spmm_csr_64f<<<sblocks, 256, 0, stream>>>(row_ptr, es2, g, out, n);
}

// Round 6
// 758.806 us; speedup vs baseline: 1.0241x; 1.0241x over previous
//
#include <hip/hip_runtime.h>
#include <hip/hip_bf16.h>
#include <cstddef>

// GCN: h0 = relu(spmm(x@W0^T)); h1 = relu(spmm(h0@W1^T)); out = spmm(h1@W2^T)
// R6: SpMM gathers 2 edges per wave (32 lanes x 8B per edge row) with x4 unroll
// -> 8 edges in flight/wave; halves combined via shfl_xor(32). Parallel
// (wave-per-row) reorder replaces serial 8-lane copy. Launch count trimmed.

typedef unsigned short ushort_t;
using frag_t = __attribute__((ext_vector_type(8))) short;   // 8 bf16
using accf4 = __attribute__((ext_vector_type(4))) float;    // 4 fp32

__device__ __forceinline__ ushort_t f2bf(float f) {
    unsigned int u = __float_as_uint(f);
    u += 0x7FFF + ((u >> 16) & 1);   // RNE
    return (ushort_t)(u >> 16);
}
__device__ __forceinline__ float bf2f(unsigned int u16) {
    return __uint_as_float(u16 << 16);
}

// ---------------- generic small kernels ----------------

__global__ __launch_bounds__(256) void zero_i32(int* p, int n) {
    int i = blockIdx.x * 256 + threadIdx.x;
    if (i < n) p[i] = 0;
}

__global__ __launch_bounds__(256) void block_totals(const int* __restrict__ counts,
                                                    int* __restrict__ bsums, int n) {
    __shared__ int s[256];
    int t = threadIdx.x;
    int i = blockIdx.x * 256 + t;
    s[t] = (i < n) ? counts[i] : 0;
    __syncthreads();
    for (int off = 128; off > 0; off >>= 1) {
        if (t < off) s[t] += s[t + off];
        __syncthreads();
    }
    if (t == 0) bsums[blockIdx.x] = s[0];
}

// single block, 512 threads: exclusive scan of nb (<=512) values in place
__global__ __launch_bounds__(512) void scan_sums(int* bsums, int nb) {
    __shared__ int s[512];
    int t = threadIdx.x;
    int v = (t < nb) ? bsums[t] : 0;
    s[t] = v;
    __syncthreads();
    for (int off = 1; off < 512; off *= 2) {
        int u = (t >= off) ? s[t - off] : 0;
        __syncthreads();
        s[t] += u;
        __syncthreads();
    }
    if (t < nb) bsums[t] = s[t] - v;  // exclusive
}

// exclusive scan with per-block offsets; optionally mirrors to out1 and writes
// a tail value (array total) at *tail.
__global__ __launch_bounds__(256) void scan_wo(const int* __restrict__ data,
                                               const int* __restrict__ offs,
                                               int* __restrict__ out0,
                                               int* __restrict__ out1,
                                               int* __restrict__ tail, int tailval,
                                               int m) {
    __shared__ int s[256];
    int t = threadIdx.x;
    int i = blockIdx.x * 256 + t;
    int v = (i < m) ? data[i] : 0;
    s[t] = v;
    __syncthreads();
    for (int off = 1; off < 256; off *= 2) {
        int u = (t >= off) ? s[t - off] : 0;
        __syncthreads();
        s[t] += u;
        __syncthreads();
    }
    int excl = s[t] - v + offs[blockIdx.x];
    if (i < m) {
        out0[i] = excl;
        if (out1) out1[i] = excl;
    }
    if (i == 0 && tail) *tail = tailval;
}

// ---------------- XCD-sliced CSR build ----------------

__global__ __launch_bounds__(256) void hist8_k(const int* __restrict__ rows,
                                               int* __restrict__ cnt8, int n, int ne) {
    int e = blockIdx.x * 256 + threadIdx.x;
    if (e >= ne) return;
    int s = blockIdx.x & 7;
    atomicAdd(&cnt8[s * n + rows[e]], 1);
}

__global__ __launch_bounds__(256) void scatter8_k(const int* __restrict__ rows,
                                                  const int* __restrict__ cols,
                                                  const float* __restrict__ vals,
                                                  int* __restrict__ cur8,
                                                  int2* __restrict__ es1, int n, int ne) {
    int e = blockIdx.x * 256 + threadIdx.x;
    if (e >= ne) return;
    int s = blockIdx.x & 7;
    int r = rows[e];
    int p = atomicAdd(&cur8[s * n + r], 1);
    es1[p] = make_int2(cols[e], __float_as_int(vals[e]));
}

// row counts from slice segment lengths + per-block totals (merged)
__global__ __launch_bounds__(256) void rowcnt_bt_k(const int* __restrict__ rp8,
                                                   int* __restrict__ cnt_row,
                                                   int* __restrict__ bsums, int n) {
    __shared__ int sm[256];
    int t = threadIdx.x;
    int i = blockIdx.x * 256 + t;
    int c = 0;
    if (i < n) {
#pragma unroll
        for (int s = 0; s < 8; s++) c += rp8[s * n + i + 1] - rp8[s * n + i];
        cnt_row[i] = c;
    }
    sm[t] = c;
    __syncthreads();
    for (int off = 128; off > 0; off >>= 1) {
        if (t < off) sm[t] += sm[t + off];
        __syncthreads();
    }
    if (t == 0) bsums[blockIdx.x] = sm[0];
}

// concatenate each row's 8 slice segments into row-contiguous CSR.
// one wave per row; lane l copies edge l (parallel, coalesced dst writes).
__global__ __launch_bounds__(256) void reorder_k(const int* __restrict__ rp8,
                                                 const int* __restrict__ row_ptr,
                                                 const int2* __restrict__ es1,
                                                 int2* __restrict__ es2, int n) {
    int row = blockIdx.x * 4 + (threadIdx.x >> 6);
    int lane = threadIdx.x & 63;
    if (row >= n) return;
    int B[8], P[9];
    P[0] = 0;
#pragma unroll
    for (int s = 0; s < 8; s++) {
        B[s] = rp8[s * n + row];
        int len = rp8[s * n + row + 1] - B[s];
        P[s + 1] = P[s] + len;
    }
    int total = P[8];
    int base = row_ptr[row];
    for (int l = lane; l < total; l += 64) {
        int s = 0;
#pragma unroll
        for (int t = 1; t < 8; t++) s += (l >= P[t]) ? 1 : 0;
        es2[base + l] = es1[B[s] + (l - P[s])];
    }
}

// ---------------- weight convert (all three in one) ----------------

__global__ __launch_bounds__(256) void wconv_k(const float* __restrict__ W0,
                                               const float* __restrict__ W1,
                                               const float* __restrict__ W2,
                                               ushort_t* __restrict__ Wb0,
                                               ushort_t* __restrict__ Wb1,
                                               ushort_t* __restrict__ Wb2) {
    int i = blockIdx.x * 256 + threadIdx.x;
    if (i < 65536) Wb0[i] = f2bf(W0[i]);
    else if (i < 81920) Wb1[i - 65536] = f2bf(W1[i - 65536]);
    else if (i < 90112) Wb2[i - 81920] = f2bf(W2[i - 81920]);
}

// ---------------- bf16 MFMA GEMM: C[M,N] = A[M,K] * W[N,K]^T ----------------
// 2-barrier pipelined K-loop: prefetch tile t+1 into registers while MFMAing
// tile t from LDS. ABF16: A already bf16; else fp32 converted at LDS write.

template <int K, int N, int BM, int BN, int BK, bool ABF16>
__global__ __launch_bounds__(256) void gemm_bf16(const void* __restrict__ Av,
                                                 const ushort_t* __restrict__ Wb,
                                                 ushort_t* __restrict__ C, int M) {
    constexpr int WM = BM / 2, WN = BN / 2;
    constexpr int TI = WM / 16, TJ = WN / 16;
    constexpr int LDA = BK + 8;
    constexpr int T = K / BK;
    constexpr int A_PER_F = BM * BK / 4 / 256;
    constexpr int A_PER_B = BM * BK / 8 / 256;
    constexpr int B_PER = BN * BK / 8 / 256;

    __shared__ __align__(16) ushort_t As[BM][LDA];
    __shared__ __align__(16) ushort_t Bs[BN][LDA];

    const int tid = threadIdx.x;
    const int lane = tid & 63;
    const int wid = tid >> 6;
    const int wm = wid >> 1, wn = wid & 1;
    const int rowBase = blockIdx.x * BM;
    const int lrow = lane & 15, kq = lane >> 4;

    float4 aF[ABF16 ? 1 : A_PER_F];
    uint4 aB[ABF16 ? A_PER_B : 1];
    uint4 bR[B_PER];

    auto loadTile = [&](int k0) {
        if constexpr (ABF16) {
            const ushort_t* A = (const ushort_t*)Av;
#pragma unroll
            for (int i = 0; i < A_PER_B; i++) {
                int idx = tid + i * 256;
                int r = idx / (BK / 8), c8 = idx % (BK / 8);
                int grow = rowBase + r;
                aB[i] = (grow < M) ? *(const uint4*)(A + (size_t)grow * K + k0 + c8 * 8)
                                   : make_uint4(0, 0, 0, 0);
            }
        } else {
            const float* A = (const float*)Av;
#pragma unroll
            for (int i = 0; i < A_PER_F; i++) {
                int idx = tid + i * 256;
                int r = idx / (BK / 4), c4 = idx % (BK / 4);
                int grow = rowBase + r;
                aF[i] = (grow < M) ? *(const float4*)(A + (size_t)grow * K + k0 + c4 * 4)
                                   : make_float4(0.f, 0.f, 0.f, 0.f);
            }
        }
#pragma unroll
        for (int i = 0; i < B_PER; i++) {
            int idx = tid + i * 256;
            int r = idx / (BK / 8), c8 = idx % (BK / 8);
            bR[i] = *(const uint4*)(Wb + (size_t)r * K + k0 + c8 * 8);
        }
    };
    auto storeTile = [&]() {
        if constexpr (ABF16) {
#pragma unroll
            for (int i = 0; i < A_PER_B; i++) {
                int idx = tid + i * 256;
                int r = idx / (BK / 8), c8 = idx % (BK / 8);
                *(uint4*)&As[r][c8 * 8] = aB[i];
            }
        } else {
#pragma unroll
            for (int i = 0; i < A_PER_F; i++) {
                int idx = tid + i * 256;
                int r = idx / (BK / 4), c4 = idx % (BK / 4);
                ushort_t p[4] = {f2bf(aF[i].x), f2bf(aF[i].y), f2bf(aF[i].z), f2bf(aF[i].w)};
                *(uint2*)&As[r][c4 * 4] = *(uint2*)p;
            }
        }
#pragma unroll
        for (int i = 0; i < B_PER; i++) {
            int idx = tid + i * 256;
            int r = idx / (BK / 8), c8 = idx % (BK / 8);
            *(uint4*)&Bs[r][c8 * 8] = bR[i];
        }
    };

    accf4 acc[TI][TJ];
#pragma unroll
    for (int i = 0; i < TI; i++)
#pragma unroll
        for (int j = 0; j < TJ; j++) acc[i][j] = accf4{0.f, 0.f, 0.f, 0.f};

    loadTile(0);
    storeTile();
    __syncthreads();

    for (int t = 0; t < T; t++) {
        if (t + 1 < T) loadTile((t + 1) * BK);   // in flight during MFMA
#pragma unroll
        for (int ks = 0; ks < BK / 32; ks++) {
            const int kb = ks * 32 + kq * 8;
            frag_t a[TI], b[TJ];
#pragma unroll
            for (int i = 0; i < TI; i++)
                a[i] = *(const frag_t*)&As[wm * WM + i * 16 + lrow][kb];
#pragma unroll
            for (int j = 0; j < TJ; j++)
                b[j] = *(const frag_t*)&Bs[wn * WN + j * 16 + lrow][kb];
#pragma unroll
            for (int i = 0; i < TI; i++)
#pragma unroll
                for (int j = 0; j < TJ; j++)
                    acc[i][j] = __builtin_amdgcn_mfma_f32_16x16x32_bf16(
                        a[i], b[j], acc[i][j], 0, 0, 0);
        }
        __syncthreads();
        if (t + 1 < T) {
            storeTile();
            __syncthreads();
        }
    }

    // epilogue: C/D layout col=lane&15, row=(lane>>4)*4+reg; write bf16
#pragma unroll
    for (int i = 0; i < TI; i++) {
#pragma unroll
        for (int j = 0; j < TJ; j++) {
            int col = wn * WN + j * 16 + lrow;
#pragma unroll
            for (int r = 0; r < 4; r++) {
                int grow = rowBase + wm * WM + i * 16 + kq * 4 + r;
                if (grow < M) C[(size_t)grow * N + col] = f2bf(acc[i][j][r]);
            }
        }
    }
}

// ---------------- SpMM (CSR, wave per row, 2 edges/wave, x4 unroll) ---------
// N=128: 32 lanes x uint2 (4 bf16) cover one 256B row; halves take even/odd
// edges; combined at the end via shfl_xor(32).

template <bool RELU>
__global__ __launch_bounds__(256) void spmm_csr_128(const int* __restrict__ row_ptr,
                                                    const int2* __restrict__ es,
                                                    const ushort_t* __restrict__ G,
                                                    ushort_t* __restrict__ H, int n) {
    int row = blockIdx.x * 4 + (threadIdx.x >> 6);
    int lane = threadIdx.x & 63;
    int half = lane >> 5, lh = lane & 31;
    if (row >= n) return;
    int s = row_ptr[row];
    int e = row_ptr[row + 1];
    float a0 = 0.f, a1 = 0.f, a2 = 0.f, a3 = 0.f;
    int p = s;
    for (; p + 7 < e; p += 8) {
        int2 e0 = es[p + half], e1 = es[p + 2 + half];
        int2 e2 = es[p + 4 + half], e3 = es[p + 6 + half];
        uint2 u0 = *(const uint2*)(G + (size_t)e0.x * 128 + lh * 4);
        uint2 u1 = *(const uint2*)(G + (size_t)e1.x * 128 + lh * 4);
        uint2 u2 = *(const uint2*)(G + (size_t)e2.x * 128 + lh * 4);
        uint2 u3 = *(const uint2*)(G + (size_t)e3.x * 128 + lh * 4);
        float v0 = __int_as_float(e0.y), v1 = __int_as_float(e1.y);
        float v2 = __int_as_float(e2.y), v3 = __int_as_float(e3.y);
        a0 += v0 * bf2f(u0.x & 0xffff); a1 += v0 * bf2f(u0.x >> 16);
        a2 += v0 * bf2f(u0.y & 0xffff); a3 += v0 * bf2f(u0.y >> 16);
        a0 += v1 * bf2f(u1.x & 0xffff); a1 += v1 * bf2f(u1.x >> 16);
        a2 += v1 * bf2f(u1.y & 0xffff); a3 += v1 * bf2f(u1.y >> 16);
        a0 += v2 * bf2f(u2.x & 0xffff); a1 += v2 * bf2f(u2.x >> 16);
        a2 += v2 * bf2f(u2.y & 0xffff); a3 += v2 * bf2f(u2.y >> 16);
        a0 += v3 * bf2f(u3.x & 0xffff); a1 += v3 * bf2f(u3.x >> 16);
        a2 += v3 * bf2f(u3.y & 0xffff); a3 += v3 * bf2f(u3.y >> 16);
    }
    for (; p + 1 < e; p += 2) {
        int2 e0 = es[p + half];
        uint2 u0 = *(const uint2*)(G + (size_t)e0.x * 128 + lh * 4);
        float v0 = __int_as_float(e0.y);
        a0 += v0 * bf2f(u0.x & 0xffff); a1 += v0 * bf2f(u0.x >> 16);
        a2 += v0 * bf2f(u0.y & 0xffff); a3 += v0 * bf2f(u0.y >> 16);
    }
    if (p < e && half == 0) {
        int2 e0 = es[p];
        uint2 u0 = *(const uint2*)(G + (size_t)e0.x * 128 + lh * 4);
        float v0 = __int_as_float(e0.y);
        a0 += v0 * bf2f(u0.x & 0xffff); a1 += v0 * bf2f(u0.x >> 16);
        a2 += v0 * bf2f(u0.y & 0xffff); a3 += v0 * bf2f(u0.y >> 16);
    }
    a0 += __shfl_xor(a0, 32); a1 += __shfl_xor(a1, 32);
    a2 += __shfl_xor(a2, 32); a3 += __shfl_xor(a3, 32);
    if (half == 0) {
        if (RELU) {
            a0 = fmaxf(a0, 0.f); a1 = fmaxf(a1, 0.f);
            a2 = fmaxf(a2, 0.f); a3 = fmaxf(a3, 0.f);
        }
        uint2 o;
        o.x = (unsigned)f2bf(a0) | ((unsigned)f2bf(a1) << 16);
        o.y = (unsigned)f2bf(a2) | ((unsigned)f2bf(a3) << 16);
        *(uint2*)(H + (size_t)row * 128 + lh * 4) = o;
    }
}

// N=64, fp32 output (final layer): 32 lanes x uint (2 bf16) per edge row.
__global__ __launch_bounds__(256) void spmm_csr_64f(const int* __restrict__ row_ptr,
                                                    const int2* __restrict__ es,
                                                    const ushort_t* __restrict__ G,
                                                    float* __restrict__ H, int n) {
    int row = blockIdx.x * 4 + (threadIdx.x >> 6);
    int lane = threadIdx.x & 63;
    int half = lane >> 5, lh = lane & 31;
    if (row >= n) return;
    int s = row_ptr[row];
    int e = row_ptr[row + 1];
    float a0 = 0.f, a1 = 0.f;
    int p = s;
    for (; p + 7 < e; p += 8) {
        int2 e0 = es[p + half], e1 = es[p + 2 + half];
        int2 e2 = es[p + 4 + half], e3 = es[p + 6 + half];
        unsigned u0 = *(const unsigned*)(G + (size_t)e0.x * 64 + lh * 2);
        unsigned u1 = *(const unsigned*)(G + (size_t)e1.x * 64 + lh * 2);
        unsigned u2 = *(const unsigned*)(G + (size_t)e2.x * 64 + lh * 2);
        unsigned u3 = *(const unsigned*)(G + (size_t)e3.x * 64 + lh * 2);
        float v0 = __int_as_float(e0.y), v1 = __int_as_float(e1.y);
        float v2 = __int_as_float(e2.y), v3 = __int_as_float(e3.y);
        a0 += v0 * bf2f(u0 & 0xffff); a1 += v0 * bf2f(u0 >> 16);
        a0 += v1 * bf2f(u1 & 0xffff); a1 += v1 * bf2f(u1 >> 16);
        a0 += v2 * bf2f(u2 & 0xffff); a1 += v2 * bf2f(u2 >> 16);
        a0 += v3 * bf2f(u3 & 0xffff); a1 += v3 * bf2f(u3 >> 16);
    }
    for (; p + 1 < e; p += 2) {
        int2 e0 = es[p + half];
        unsigned u0 = *(const unsigned*)(G + (size_t)e0.x * 64 + lh * 2);
        float v0 = __int_as_float(e0.y);
        a0 += v0 * bf2f(u0 & 0xffff); a1 += v0 * bf2f(u0 >> 16);
    }
    if (p < e && half == 0) {
        int2 e0 = es[p];
        unsigned u0 = *(const unsigned*)(G + (size_t)e0.x * 64 + lh * 2);
        float v0 = __int_as_float(e0.y);
        a0 += v0 * bf2f(u0 & 0xffff); a1 += v0 * bf2f(u0 >> 16);
    }
    a0 += __shfl_xor(a0, 32); a1 += __shfl_xor(a1, 32);
    if (half == 0) {
        float2 o = make_float2(a0, a1);
        *(float2*)(H + (size_t)row * 64 + lh * 2) = o;
    }
}

static inline size_t align_up(size_t x, size_t a) { return (x + a - 1) & ~(a - 1); }

extern "C" void kernel_launch(void* const* d_in, const int* in_sizes, int n_in,
                              void* d_out, int out_size, void* d_ws, size_t ws_size,
                              hipStream_t stream) {
    const float* x = (const float*)d_in[0];
    const int* rows = (const int*)d_in[1];
    const int* cols = (const int*)d_in[2];
    const float* vals = (const float*)d_in[3];
    const float* W0 = (const float*)d_in[4];
    const float* W1 = (const float*)d_in[5];
    const float* W2 = (const float*)d_in[6];
    float* out = (float*)d_out;

    const int IN = 512, HID = 128, OUT = 64;
    const int n = in_sizes[0] / IN;   // 100000
    const int ne = in_sizes[1];       // 1600000

    // workspace carve-up
    char* ws = (char*)d_ws;
    size_t off = 0;
    ushort_t* g = (ushort_t*)(ws + off); off = align_up(off + (size_t)n * HID * 2, 512);
    ushort_t* h = (ushort_t*)(ws + off); off = align_up(off + (size_t)n * HID * 2, 512);
    int2* es1 = (int2*)(ws + off); off = align_up(off + (size_t)ne * 8, 512);
    int2* es2 = (int2*)(ws + off); off = align_up(off + (size_t)ne * 8, 512);
    int* cnt8 = (int*)(ws + off); off = align_up(off + (size_t)8 * n * 4, 512);
    int* rp8 = (int*)(ws + off); off = align_up(off + ((size_t)8 * n + 1) * 4, 512);
    int* cur8 = (int*)(ws + off); off = align_up(off + (size_t)8 * n * 4, 512);
    int* cnt_row = (int*)(ws + off); off = align_up(off + (size_t)n * 4, 512);
    int* row_ptr = (int*)(ws + off); off = align_up(off + (size_t)(n + 1) * 4, 512);
    int* bsum0 = (int*)(ws + off); off = align_up(off + 4096 * 4, 512);
    int* bsum1 = (int*)(ws + off); off = align_up(off + 512 * 4, 512);
    int* off0 = (int*)(ws + off); off = align_up(off + 4096 * 4, 512);
    int* bsums_r = (int*)(ws + off); off = align_up(off + 512 * 4, 512);
    ushort_t* Wb0 = (ushort_t*)(ws + off); off = align_up(off + (size_t)HID * IN * 2, 512);
    ushort_t* Wb1 = (ushort_t*)(ws + off); off = align_up(off + (size_t)HID * HID * 2, 512);
    ushort_t* Wb2 = (ushort_t*)(ws + off); off = align_up(off + (size_t)OUT * HID * 2, 512);

    const int nb = (n + 255) / 256;        // 391
    const int eb = (ne + 255) / 256;       // 6250
    const int m8 = 8 * n;                  // 800000
    const int nb8 = (m8 + 255) / 256;      // 3125
    const int nb8b = (nb8 + 255) / 256;    // 13

    // ---- sliced CSR build ----
    zero_i32<<<nb8, 256, 0, stream>>>(cnt8, m8);
    hist8_k<<<eb, 256, 0, stream>>>(rows, cnt8, n, ne);
    block_totals<<<nb8, 256, 0, stream>>>(cnt8, bsum0, m8);
    block_totals<<<nb8b, 256, 0, stream>>>(bsum0, bsum1, nb8);
    scan_sums<<<1, 512, 0, stream>>>(bsum1, nb8b);
    scan_wo<<<nb8b, 256, 0, stream>>>(bsum0, bsum1, off0, nullptr, nullptr, 0, nb8);
    scan_wo<<<nb8, 256, 0, stream>>>(cnt8, off0, rp8, cur8, rp8 + m8, ne, m8);
    scatter8_k<<<eb, 256, 0, stream>>>(rows, cols, vals, cur8, es1, n, ne);

    // ---- row_ptr from slice segment lengths ----
    rowcnt_bt_k<<<nb, 256, 0, stream>>>(rp8, cnt_row, bsums_r, n);
    scan_sums<<<1, 512, 0, stream>>>(bsums_r, nb);
    scan_wo<<<nb, 256, 0, stream>>>(cnt_row, bsums_r, row_ptr, nullptr, row_ptr + n, ne, n);

    // ---- reorder to row-contiguous CSR (wave per row) ----
    reorder_k<<<(n + 3) / 4, 256, 0, stream>>>(rp8, row_ptr, es1, es2, n);

    // ---- weights -> bf16 (single kernel) ----
    wconv_k<<<(90112 + 255) / 256, 256, 0, stream>>>(W0, W1, W2, Wb0, Wb1, Wb2);

    const int gblocks = (n + 127) / 128;
    const int sblocks = (n + 3) / 4;

    // ---- layer 0 ----
    gemm_bf16<512, 128, 128, 128, 64, false><<<gblocks, 256, 0, stream>>>(x, Wb0, g, n);
    spmm_csr_128<true><<<sblocks, 256, 0, stream>>>(row_ptr, es2, g, h, n);

    // ---- layer 1 ----
    gemm_bf16<128, 128, 128, 128, 64, true><<<gblocks, 256, 0, stream>>>(h, Wb1, g, n);
    spmm_csr_128<true><<<sblocks, 256, 0, stream>>>(row_ptr, es2, g, h, n);

    // ---- layer 2 ----
    gemm_bf16<128, 64, 128, 64, 64, true><<<gblocks, 256, 0, stream>>>(h, Wb2, g, n);
    spmm_csr_64f<<<sblocks, 256, 0, stream>>>(row_ptr, es2, g, out, n);
}